// Round 4
// baseline (518.061 us; speedup 1.0000x reference)
//
#include <hip/hip_runtime.h>

#define NN 256
#define XD 256
#define ED 128

typedef __attribute__((ext_vector_type(8))) short short8;
typedef __attribute__((ext_vector_type(4))) float f32x4;

__device__ __forceinline__ unsigned short f2bf(float f) {
    unsigned u = __builtin_bit_cast(unsigned, f);
    u += 0x7FFF + ((u >> 16) & 1);
    return (unsigned short)(u >> 16);
}

#define MFMA16(a, b, c) __builtin_amdgcn_mfma_f32_16x16x32_bf16(a, b, c, 0, 0, 0)

__device__ __forceinline__ short8 pack8(float4 a, float4 b) {
    short8 r;
    r[0] = (short)f2bf(a.x); r[1] = (short)f2bf(a.y);
    r[2] = (short)f2bf(a.z); r[3] = (short)f2bf(a.w);
    r[4] = (short)f2bf(b.x); r[5] = (short)f2bf(b.y);
    r[6] = (short)f2bf(b.z); r[7] = (short)f2bf(b.w);
    return r;
}

// ---------------------------------------------------------------------------
// Weight prep.
//  blocks 0..255  : WqT/WkT/WvT/WxoT  [n][k] bf16 (transpose via LDS)
//  blocks 256..319: WemT/WeaT         [xdim][edim] bf16
//  blocks 320..351: WeoP — k-PERMUTED: WeoP[ed][kk] = Weo[sigma(kk)][ed]
//    sigma(kk): kk = c*32+q*8+jj -> (2c + (jj>>2))*16 + q*4 + (jj&3)
//    so GEMM2 B-frag chunk c == lane's own GEMM1 accs (mt=2c,2c+1) packed.
// ---------------------------------------------------------------------------
__global__ __launch_bounds__(256) void wprep_kernel(
    const float* __restrict__ Wq, const float* __restrict__ Wk,
    const float* __restrict__ Wv, const float* __restrict__ Wxo,
    const float* __restrict__ Wem, const float* __restrict__ Wea,
    const float* __restrict__ Weo,
    short* __restrict__ WqT, short* __restrict__ WkT,
    short* __restrict__ WvT, short* __restrict__ WxoT,
    short* __restrict__ WemT, short* __restrict__ WeaT,
    short* __restrict__ WeoP)
{
    __shared__ float sT[32][33];
    int blk = blockIdx.x;
    if (blk >= 320) {   // WeoP permuted gather
        int t = (blk - 320) * 256 + threadIdx.x;   // 0..8191
        int n = t >> 6;
        int kk0 = (t & 63) * 4;
        #pragma unroll
        for (int r = 0; r < 4; ++r) {
            int kk = kk0 + r;
            int sigma = (((kk >> 5) * 2 + ((kk >> 2) & 1)) << 4) +
                        (((kk >> 3) & 3) << 2) + (kk & 3);
            WeoP[n * 256 + kk] = (short)f2bf(Weo[sigma * 128 + n]);
        }
        return;
    }
    const float* src; short* dst; int din, dout, tile;
    if (blk < 256) {
        int m = blk >> 6; tile = blk & 63; din = 256; dout = 256;
        src = m == 0 ? Wq : (m == 1 ? Wk : (m == 2 ? Wv : Wxo));
        dst = m == 0 ? WqT : (m == 1 ? WkT : (m == 2 ? WvT : WxoT));
    } else {
        int m = (blk - 256) >> 5; tile = (blk - 256) & 31; din = 128; dout = 256;
        src = m == 0 ? Wem : Wea; dst = m == 0 ? WemT : WeaT;
    }
    int ksh = (din == 256) ? 3 : 2;
    int kt = tile & ((1 << ksh) - 1);
    int nt = tile >> ksh;
    int c = threadIdx.x & 31, rbase = threadIdx.x >> 5;
    #pragma unroll
    for (int p = 0; p < 4; ++p) {
        int r = rbase + p * 8;
        sT[r][c] = src[(kt * 32 + r) * dout + nt * 32 + c];
    }
    __syncthreads();
    #pragma unroll
    for (int p = 0; p < 4; ++p) {
        int r = rbase + p * 8;
        dst[(nt * 32 + r) * din + kt * 32 + c] = (short)f2bf(sT[c][r]);
    }
}

// ---------------------------------------------------------------------------
// Q/K projection. Q row-major pre-scaled by 1/sqrt(32); K row-major + bias.
// grid = 16 m-tiles (64 rows) x 2 mats.
// ---------------------------------------------------------------------------
__global__ __launch_bounds__(512) void proj_qk_kernel(
    const float* __restrict__ x, const short* __restrict__ WqT,
    const short* __restrict__ WkT, const float* __restrict__ bq,
    const float* __restrict__ bk, float* __restrict__ Qs,
    float* __restrict__ Kb)
{
    __shared__ unsigned short sX[64 * 264];
    const int blk = blockIdx.x;
    const int mtile = blk >> 1;
    const int mat   = blk & 1;
    const int tid = threadIdx.x, wave = tid >> 6, lane = tid & 63;
    const int quad = lane >> 4, l16 = lane & 15;

    {
        const float4* src4 = (const float4*)(x + (size_t)mtile * 64 * XD);
        #pragma unroll
        for (int it = 0; it < 8; ++it) {
            int idx4 = tid + it * 512;
            float4 v = src4[idx4];
            int elem = idx4 * 4, row = elem >> 8, col = elem & 255;
            short4 p = make_short4((short)f2bf(v.x), (short)f2bf(v.y),
                                   (short)f2bf(v.z), (short)f2bf(v.w));
            *(short4*)&sX[row * 264 + col] = p;
        }
    }
    __syncthreads();

    const short* WT   = mat ? WkT : WqT;
    const float* bias = mat ? bk : bq;
    float* out        = mat ? Kb : Qs;
    const float scale = mat ? 1.0f : 0.17677669529663687f;
    const int c0 = wave * 32;

    f32x4 acc[4][2] = {};
    for (int ks = 0; ks < 8; ++ks) {
        short8 bfrag[2];
        #pragma unroll
        for (int ct = 0; ct < 2; ++ct)
            bfrag[ct] = *(const short8*)&WT[(c0 + ct * 16 + l16) * 256 + ks * 32 + quad * 8];
        #pragma unroll
        for (int mt = 0; mt < 4; ++mt) {
            short8 a = *(const short8*)&sX[(mt * 16 + l16) * 264 + ks * 32 + quad * 8];
            acc[mt][0] = MFMA16(a, bfrag[0], acc[mt][0]);
            acc[mt][1] = MFMA16(a, bfrag[1], acc[mt][1]);
        }
    }
    #pragma unroll
    for (int mt = 0; mt < 4; ++mt)
        #pragma unroll
        for (int ct = 0; ct < 2; ++ct) {
            int cc = c0 + ct * 16 + l16;
            float bb = bias[cc];
            #pragma unroll
            for (int r = 0; r < 4; ++r)
                out[(size_t)(mtile * 64 + mt * 16 + quad * 4 + r) * 256 + cc] =
                    (acc[mt][ct][r] + bb) * scale;
        }
}

// ---------------------------------------------------------------------------
// V = x@Wv + bv (bf16 in LDS), then newX = V@Wxo + bxo.
// (softmax over i sums to 1, so weighted_V == V exactly.)
// ---------------------------------------------------------------------------
__global__ __launch_bounds__(512) void proj_vx_kernel(
    const float* __restrict__ x, const short* __restrict__ WvT,
    const float* __restrict__ bv, const short* __restrict__ WxoT,
    const float* __restrict__ bxo, float* __restrict__ outX)
{
    __shared__ unsigned short sX[64 * 264];
    __shared__ unsigned short sV[64 * 264];
    const int mtile = blockIdx.x;
    const int tid = threadIdx.x, wave = tid >> 6, lane = tid & 63;
    const int quad = lane >> 4, l16 = lane & 15;

    {
        const float4* src4 = (const float4*)(x + (size_t)mtile * 64 * XD);
        #pragma unroll
        for (int it = 0; it < 8; ++it) {
            int idx4 = tid + it * 512;
            float4 v = src4[idx4];
            int elem = idx4 * 4, row = elem >> 8, col = elem & 255;
            short4 p = make_short4((short)f2bf(v.x), (short)f2bf(v.y),
                                   (short)f2bf(v.z), (short)f2bf(v.w));
            *(short4*)&sX[row * 264 + col] = p;
        }
    }
    __syncthreads();

    const int c0 = wave * 32;
    f32x4 acc[4][2] = {};
    for (int ks = 0; ks < 8; ++ks) {
        short8 bfrag[2];
        #pragma unroll
        for (int ct = 0; ct < 2; ++ct)
            bfrag[ct] = *(const short8*)&WvT[(c0 + ct * 16 + l16) * 256 + ks * 32 + quad * 8];
        #pragma unroll
        for (int mt = 0; mt < 4; ++mt) {
            short8 a = *(const short8*)&sX[(mt * 16 + l16) * 264 + ks * 32 + quad * 8];
            acc[mt][0] = MFMA16(a, bfrag[0], acc[mt][0]);
            acc[mt][1] = MFMA16(a, bfrag[1], acc[mt][1]);
        }
    }
    #pragma unroll
    for (int mt = 0; mt < 4; ++mt)
        #pragma unroll
        for (int ct = 0; ct < 2; ++ct) {
            int cc = c0 + ct * 16 + l16;
            float bb = bv[cc];
            #pragma unroll
            for (int r = 0; r < 4; ++r)
                sV[(mt * 16 + quad * 4 + r) * 264 + cc] = f2bf(acc[mt][ct][r] + bb);
        }
    __syncthreads();

    f32x4 acc2[4][2] = {};
    for (int ks = 0; ks < 8; ++ks) {
        short8 bfrag[2];
        #pragma unroll
        for (int ct = 0; ct < 2; ++ct)
            bfrag[ct] = *(const short8*)&WxoT[(c0 + ct * 16 + l16) * 256 + ks * 32 + quad * 8];
        #pragma unroll
        for (int mt = 0; mt < 4; ++mt) {
            short8 a = *(const short8*)&sV[(mt * 16 + l16) * 264 + ks * 32 + quad * 8];
            acc2[mt][0] = MFMA16(a, bfrag[0], acc2[mt][0]);
            acc2[mt][1] = MFMA16(a, bfrag[1], acc2[mt][1]);
        }
    }
    #pragma unroll
    for (int mt = 0; mt < 4; ++mt)
        #pragma unroll
        for (int ct = 0; ct < 2; ++ct) {
            int cc = c0 + ct * 16 + l16;
            float bb = bxo[cc];
            #pragma unroll
            for (int r = 0; r < 4; ++r)
                outX[(size_t)(mtile * 64 + mt * 16 + quad * 4 + r) * 256 + cc] =
                    acc2[mt][ct][r] + bb;
        }
}

// ---------------------------------------------------------------------------
// Fused edge kernel v4 — transposed GEMMs, no LDS, no barriers.
// Wave owns 32 j-rows of one (b,i). GEMM1: E^T = W^T·e^T (A=weights streamed,
// B=e-frags register-resident). Combine in C-layout (row=xdim, col=j).
// GEMM2: newE^T = WeoP·Y^T, where the sigma-permuted WeoP makes each B-frag
// chunk exactly the lane's own packed GEMM1 accumulators.
// ---------------------------------------------------------------------------
__global__ __launch_bounds__(256, 3) void fused_edge_kernel(
    const float* __restrict__ e, const float* __restrict__ Qs,
    const float* __restrict__ Kb, const short* __restrict__ WemT,
    const short* __restrict__ WeaT, const short* __restrict__ WeoP,
    const float* __restrict__ bem, const float* __restrict__ bea,
    const float* __restrict__ beo, float* __restrict__ outE)
{
    const int blk  = blockIdx.x;              // 2048 blocks
    const int jh   = blk & 1;
    const int i    = (blk >> 1) & 255;
    const int b    = blk >> 9;
    const int wave = threadIdx.x >> 6;
    const int lane = threadIdx.x & 63;
    const int q    = lane >> 4;
    const int l16  = lane & 15;
    const int j0   = jh * 128 + wave * 32;    // wave's 32 j-rows

    // ---- e B-frags: register-resident. Be[nt][ks] covers e[j0+nt*16+l16][*]
    short8 Be[2][4];
    {
        const size_t erow = ((size_t)(b * NN + i) * NN + j0 + l16) * ED;
        #pragma unroll
        for (int nt = 0; nt < 2; ++nt) {
            const float* ep = e + erow + nt * 16 * ED + q * 8;
            #pragma unroll
            for (int ks = 0; ks < 4; ++ks) {
                float4 lo = *(const float4*)(ep + ks * 32);
                float4 hi = *(const float4*)(ep + ks * 32 + 4);
                Be[nt][ks] = pack8(lo, hi);
            }
        }
    }

    const float* Qrow = Qs + (size_t)(b * NN + i) * XD;
    const size_t krow0 = ((size_t)b * NN + j0 + l16) * XD;

    f32x4 acc2[8][2] = {};   // newE^T: [ed-tile][j-tile]

    #pragma unroll
    for (int c = 0; c < 8; ++c) {
        short8 B2[2];
        #pragma unroll
        for (int h = 0; h < 2; ++h) {
            const int mt = 2 * c + h;
            const int xb = mt * 16 + q * 4;
            // GEMM1: E1,E2 tiles for xdim rows [mt*16,+16), both j-tiles
            f32x4 a1[2] = {}, a2[2] = {};
            #pragma unroll
            for (int ks = 0; ks < 4; ++ks) {
                short8 Am = *(const short8*)&WemT[(mt * 16 + l16) * 128 + ks * 32 + q * 8];
                short8 Aa = *(const short8*)&WeaT[(mt * 16 + l16) * 128 + ks * 32 + q * 8];
                a1[0] = MFMA16(Am, Be[0][ks], a1[0]);
                a1[1] = MFMA16(Am, Be[1][ks], a1[1]);
                a2[0] = MFMA16(Aa, Be[0][ks], a2[0]);
                a2[1] = MFMA16(Aa, Be[1][ks], a2[1]);
            }
            // combine: Y = qs*kv*(E1+bem+1) + (E2+bea), pack to B2 halves
            float4 qs = *(const float4*)&Qrow[xb];
            float4 bm = *(const float4*)&bem[xb];
            float4 ba = *(const float4*)&bea[xb];
            #pragma unroll
            for (int nt = 0; nt < 2; ++nt) {
                float4 kv = *(const float4*)&Kb[krow0 + nt * 16 * XD + xb];
                float y0 = qs.x * kv.x * (a1[nt][0] + bm.x + 1.0f) + a2[nt][0] + ba.x;
                float y1 = qs.y * kv.y * (a1[nt][1] + bm.y + 1.0f) + a2[nt][1] + ba.y;
                float y2 = qs.z * kv.z * (a1[nt][2] + bm.z + 1.0f) + a2[nt][2] + ba.z;
                float y3 = qs.w * kv.w * (a1[nt][3] + bm.w + 1.0f) + a2[nt][3] + ba.w;
                B2[nt][h * 4 + 0] = (short)f2bf(y0);
                B2[nt][h * 4 + 1] = (short)f2bf(y1);
                B2[nt][h * 4 + 2] = (short)f2bf(y2);
                B2[nt][h * 4 + 3] = (short)f2bf(y3);
            }
        }
        // GEMM2 k-chunk c: acc2 += WeoP-frag x B2
        #pragma unroll
        for (int m2 = 0; m2 < 8; ++m2) {
            short8 A2 = *(const short8*)&WeoP[(m2 * 16 + l16) * 256 + c * 32 + q * 8];
            acc2[m2][0] = MFMA16(A2, B2[0], acc2[m2][0]);
            acc2[m2][1] = MFMA16(A2, B2[1], acc2[m2][1]);
        }
    }

    // ---- epilogue: + beo, store newE^T C-layout as float4 over ed
    float* outBase = outE + ((size_t)(b * NN + i) * NN + j0 + l16) * ED;
    #pragma unroll
    for (int m2 = 0; m2 < 8; ++m2) {
        const int ed = m2 * 16 + q * 4;
        float4 bo = *(const float4*)&beo[ed];
        #pragma unroll
        for (int nt = 0; nt < 2; ++nt) {
            float4 st;
            st.x = acc2[m2][nt][0] + bo.x;
            st.y = acc2[m2][nt][1] + bo.y;
            st.z = acc2[m2][nt][2] + bo.z;
            st.w = acc2[m2][nt][3] + bo.w;
            *(float4*)(outBase + (size_t)nt * 16 * ED + ed) = st;
        }
    }
}

extern "C" void kernel_launch(void* const* d_in, const int* in_sizes, int n_in,
                              void* d_out, int out_size, void* d_ws, size_t ws_size,
                              hipStream_t stream)
{
    const float* x   = (const float*)d_in[0];
    const float* e   = (const float*)d_in[1];
    const float* Wq  = (const float*)d_in[2];
    const float* bq  = (const float*)d_in[3];
    const float* Wk  = (const float*)d_in[4];
    const float* bk  = (const float*)d_in[5];
    const float* Wv  = (const float*)d_in[6];
    const float* bv  = (const float*)d_in[7];
    const float* Wem = (const float*)d_in[8];
    const float* bem = (const float*)d_in[9];
    const float* Wea = (const float*)d_in[10];
    const float* bea = (const float*)d_in[11];
    const float* Wxo = (const float*)d_in[12];
    const float* bxo = (const float*)d_in[13];
    const float* Weo = (const float*)d_in[14];
    const float* beo = (const float*)d_in[15];

    float* outX = (float*)d_out;                 // newX: 262144 f32
    float* outE = (float*)d_out + 262144;        // newE: 33554432 f32

    float* Qs   = (float*)d_ws;                  // [1024][256] f32 (scaled)
    float* Kb   = Qs + 262144;                   // [1024][256] f32 (row-major)
    short* WqT  = (short*)(Kb + 262144);         // [256][256] bf16
    short* WkT  = WqT + 65536;
    short* WvT  = WkT + 65536;
    short* WxoT = WvT + 65536;
    short* WemT = WxoT + 65536;                  // [256][128] bf16
    short* WeaT = WemT + 32768;
    short* WeoP = WeaT + 32768;                  // [128][256] bf16, k-permuted

    hipLaunchKernelGGL(wprep_kernel, dim3(352), dim3(256), 0, stream,
                       Wq, Wk, Wv, Wxo, Wem, Wea, Weo,
                       WqT, WkT, WvT, WxoT, WemT, WeaT, WeoP);
    hipLaunchKernelGGL(proj_qk_kernel, dim3(32), dim3(512), 0, stream,
                       x, WqT, WkT, bq, bk, Qs, Kb);
    hipLaunchKernelGGL(proj_vx_kernel, dim3(16), dim3(512), 0, stream,
                       x, WvT, bv, WxoT, bxo, outX);
    hipLaunchKernelGGL(fused_edge_kernel, dim3(2048), dim3(256), 0, stream,
                       e, Qs, Kb, WemT, WeaT, WeoP, bem, bea, beo, outE);
}

// Round 5
// 434.051 us; speedup vs baseline: 1.1935x; 1.1935x over previous
//
#include <hip/hip_runtime.h>

#define NN 256
#define XD 256
#define ED 128

typedef __attribute__((ext_vector_type(8))) short short8;
typedef __attribute__((ext_vector_type(4))) float f32x4;

__device__ __forceinline__ unsigned short f2bf(float f) {
    unsigned u = __builtin_bit_cast(unsigned, f);
    u += 0x7FFF + ((u >> 16) & 1);
    return (unsigned short)(u >> 16);
}
__device__ __forceinline__ float bf2f(unsigned short h) {
    unsigned u = ((unsigned)h) << 16;
    return __builtin_bit_cast(float, u);
}

#define MFMA16(a, b, c) __builtin_amdgcn_mfma_f32_16x16x32_bf16(a, b, c, 0, 0, 0)

// ---------------------------------------------------------------------------
// Weight prep: transpose + bf16-convert all 7 weights to [n][k] layout.
// ---------------------------------------------------------------------------
__global__ __launch_bounds__(256) void wprep_kernel(
    const float* __restrict__ Wq, const float* __restrict__ Wk,
    const float* __restrict__ Wv, const float* __restrict__ Wxo,
    const float* __restrict__ Wem, const float* __restrict__ Wea,
    const float* __restrict__ Weo,
    short* __restrict__ WqT, short* __restrict__ WkT,
    short* __restrict__ WvT, short* __restrict__ WxoT,
    short* __restrict__ WemT, short* __restrict__ WeaT,
    short* __restrict__ WeoT)
{
    __shared__ float sT[32][33];
    int blk = blockIdx.x;
    const float* src; short* dst; int din, dout, tile;
    if (blk < 256) {
        int m = blk >> 6; tile = blk & 63; din = 256; dout = 256;
        src = m == 0 ? Wq : (m == 1 ? Wk : (m == 2 ? Wv : Wxo));
        dst = m == 0 ? WqT : (m == 1 ? WkT : (m == 2 ? WvT : WxoT));
    } else if (blk < 320) {
        int m = (blk - 256) >> 5; tile = (blk - 256) & 31; din = 128; dout = 256;
        src = m == 0 ? Wem : Wea; dst = m == 0 ? WemT : WeaT;
    } else {
        tile = blk - 320; din = 256; dout = 128;
        src = Weo; dst = WeoT;
    }
    int ksh = (din == 256) ? 3 : 2;
    int kt = tile & ((1 << ksh) - 1);
    int nt = tile >> ksh;
    int c = threadIdx.x & 31, rbase = threadIdx.x >> 5;
    #pragma unroll
    for (int p = 0; p < 4; ++p) {
        int r = rbase + p * 8;
        sT[r][c] = src[(kt * 32 + r) * dout + nt * 32 + c];
    }
    __syncthreads();
    #pragma unroll
    for (int p = 0; p < 4; ++p) {
        int r = rbase + p * 8;
        dst[(nt * 32 + r) * din + kt * 32 + c] = (short)f2bf(sT[c][r]);
    }
}

// ---------------------------------------------------------------------------
// Q/K projection. Q row-major fp32 pre-scaled by 1/sqrt(32).
// K stored bf16 TRANSPOSED: Kbf[b][c][j], so fused loads K as short4 over j.
// ---------------------------------------------------------------------------
__global__ __launch_bounds__(512) void proj_qk_kernel(
    const float* __restrict__ x, const short* __restrict__ WqT,
    const short* __restrict__ WkT, const float* __restrict__ bq,
    const float* __restrict__ bk, float* __restrict__ Qs,
    unsigned short* __restrict__ Kbf)
{
    __shared__ unsigned short sX[64 * 264];
    const int blk = blockIdx.x;
    const int mtile = blk >> 1;   // 64-row tile of the 1024 rows
    const int mat   = blk & 1;    // 0: Q, 1: K
    const int tid = threadIdx.x, wave = tid >> 6, lane = tid & 63;
    const int quad = lane >> 4, l16 = lane & 15;

    {
        const float4* src4 = (const float4*)(x + (size_t)mtile * 64 * XD);
        #pragma unroll
        for (int it = 0; it < 8; ++it) {
            int idx4 = tid + it * 512;
            float4 v = src4[idx4];
            int elem = idx4 * 4, row = elem >> 8, col = elem & 255;
            short4 p = make_short4((short)f2bf(v.x), (short)f2bf(v.y),
                                   (short)f2bf(v.z), (short)f2bf(v.w));
            *(short4*)&sX[row * 264 + col] = p;
        }
    }
    __syncthreads();

    const short* WT   = mat ? WkT : WqT;
    const float* bias = mat ? bk : bq;
    const int c0 = wave * 32;

    f32x4 acc[4][2] = {};
    for (int ks = 0; ks < 8; ++ks) {
        short8 bfrag[2];
        #pragma unroll
        for (int ct = 0; ct < 2; ++ct)
            bfrag[ct] = *(const short8*)&WT[(c0 + ct * 16 + l16) * 256 + ks * 32 + quad * 8];
        #pragma unroll
        for (int mt = 0; mt < 4; ++mt) {
            short8 a = *(const short8*)&sX[(mt * 16 + l16) * 264 + ks * 32 + quad * 8];
            acc[mt][0] = MFMA16(a, bfrag[0], acc[mt][0]);
            acc[mt][1] = MFMA16(a, bfrag[1], acc[mt][1]);
        }
    }

    if (mat == 0) {
        #pragma unroll
        for (int mt = 0; mt < 4; ++mt)
            #pragma unroll
            for (int ct = 0; ct < 2; ++ct) {
                int cc = c0 + ct * 16 + l16;
                float bb = bias[cc];
                #pragma unroll
                for (int r = 0; r < 4; ++r)
                    Qs[(size_t)(mtile * 64 + mt * 16 + quad * 4 + r) * 256 + cc] =
                        (acc[mt][ct][r] + bb) * 0.17677669529663687f;
            }
    } else {
        int b = mtile >> 2, j0p = (mtile & 3) * 64;
        #pragma unroll
        for (int mt = 0; mt < 4; ++mt)
            #pragma unroll
            for (int ct = 0; ct < 2; ++ct) {
                int cc = c0 + ct * 16 + l16;
                float bb = bias[cc];
                short4 st;
                st.x = (short)f2bf(acc[mt][ct][0] + bb);
                st.y = (short)f2bf(acc[mt][ct][1] + bb);
                st.z = (short)f2bf(acc[mt][ct][2] + bb);
                st.w = (short)f2bf(acc[mt][ct][3] + bb);
                *(short4*)&Kbf[(size_t)(b * 256 + cc) * 256 + j0p + mt * 16 + quad * 4] = st;
            }
    }
}

// ---------------------------------------------------------------------------
// V = x@Wv + bv (bf16 in LDS), then newX = V@Wxo + bxo.
// (softmax over i sums to 1, so weighted_V == V exactly.)
// ---------------------------------------------------------------------------
__global__ __launch_bounds__(512) void proj_vx_kernel(
    const float* __restrict__ x, const short* __restrict__ WvT,
    const float* __restrict__ bv, const short* __restrict__ WxoT,
    const float* __restrict__ bxo, float* __restrict__ outX)
{
    __shared__ unsigned short sX[64 * 264];
    __shared__ unsigned short sV[64 * 264];
    const int mtile = blockIdx.x;
    const int tid = threadIdx.x, wave = tid >> 6, lane = tid & 63;
    const int quad = lane >> 4, l16 = lane & 15;

    {
        const float4* src4 = (const float4*)(x + (size_t)mtile * 64 * XD);
        #pragma unroll
        for (int it = 0; it < 8; ++it) {
            int idx4 = tid + it * 512;
            float4 v = src4[idx4];
            int elem = idx4 * 4, row = elem >> 8, col = elem & 255;
            short4 p = make_short4((short)f2bf(v.x), (short)f2bf(v.y),
                                   (short)f2bf(v.z), (short)f2bf(v.w));
            *(short4*)&sX[row * 264 + col] = p;
        }
    }
    __syncthreads();

    const int c0 = wave * 32;
    f32x4 acc[4][2] = {};
    for (int ks = 0; ks < 8; ++ks) {
        short8 bfrag[2];
        #pragma unroll
        for (int ct = 0; ct < 2; ++ct)
            bfrag[ct] = *(const short8*)&WvT[(c0 + ct * 16 + l16) * 256 + ks * 32 + quad * 8];
        #pragma unroll
        for (int mt = 0; mt < 4; ++mt) {
            short8 a = *(const short8*)&sX[(mt * 16 + l16) * 264 + ks * 32 + quad * 8];
            acc[mt][0] = MFMA16(a, bfrag[0], acc[mt][0]);
            acc[mt][1] = MFMA16(a, bfrag[1], acc[mt][1]);
        }
    }
    #pragma unroll
    for (int mt = 0; mt < 4; ++mt)
        #pragma unroll
        for (int ct = 0; ct < 2; ++ct) {
            int cc = c0 + ct * 16 + l16;
            float bb = bv[cc];
            #pragma unroll
            for (int r = 0; r < 4; ++r)
                sV[(mt * 16 + quad * 4 + r) * 264 + cc] = f2bf(acc[mt][ct][r] + bb);
        }
    __syncthreads();

    f32x4 acc2[4][2] = {};
    for (int ks = 0; ks < 8; ++ks) {
        short8 bfrag[2];
        #pragma unroll
        for (int ct = 0; ct < 2; ++ct)
            bfrag[ct] = *(const short8*)&WxoT[(c0 + ct * 16 + l16) * 256 + ks * 32 + quad * 8];
        #pragma unroll
        for (int mt = 0; mt < 4; ++mt) {
            short8 a = *(const short8*)&sV[(mt * 16 + l16) * 264 + ks * 32 + quad * 8];
            acc2[mt][0] = MFMA16(a, bfrag[0], acc2[mt][0]);
            acc2[mt][1] = MFMA16(a, bfrag[1], acc2[mt][1]);
        }
    }
    #pragma unroll
    for (int mt = 0; mt < 4; ++mt)
        #pragma unroll
        for (int ct = 0; ct < 2; ++ct) {
            int cc = c0 + ct * 16 + l16;
            float bb = bxo[cc];
            #pragma unroll
            for (int r = 0; r < 4; ++r)
                outX[(size_t)(mtile * 64 + mt * 16 + quad * 4 + r) * 256 + cc] =
                    acc2[mt][ct][r] + bb;
        }
}

// ---------------------------------------------------------------------------
// Fused edge kernel v5: block = (b,i), 4 j-tiles of 64 rows, software-
// pipelined. e(t+1) prefetched to registers during tile t compute; K(t+1)
// (bf16) prefetched during GEMM2; register-resident weight frags; 2 barriers
// per tile. Dataflow per tile identical to v3 (verified).
// ---------------------------------------------------------------------------
__global__ __launch_bounds__(256, 2) void fused_edge_kernel(
    const float* __restrict__ e, const float* __restrict__ Qs,
    const unsigned short* __restrict__ Kbf, const short* __restrict__ WemT,
    const short* __restrict__ WeaT, const short* __restrict__ WeoT,
    const float* __restrict__ bem, const float* __restrict__ bea,
    const float* __restrict__ beo, float* __restrict__ outE)
{
    __shared__ unsigned short sE[64 * 140];   // e tile bf16, pitch 140
    __shared__ unsigned short sY[64 * 264];   // Y tile bf16, pitch 264

    const int blk  = blockIdx.x;              // 1024 blocks = (b,i)
    const int i    = blk & 255;
    const int b    = blk >> 8;
    const int tid  = threadIdx.x;
    const int wave = tid >> 6;
    const int lane = tid & 63;
    const int q    = lane >> 4;
    const int l16  = lane & 15;
    const int c0w  = wave * 32;

    const float* eBase = e + (size_t)((b * NN + i) * NN) * ED;
    const unsigned short* kB = Kbf + (size_t)b * 256 * 256;
    const float* Qrow = Qs + (size_t)(b * NN + i) * XD;

    // block-invariant per-lane scalars (both passes)
    float qsv[2][2], bmv[2][2], bav[2][2], bo[2];
    #pragma unroll
    for (int p = 0; p < 2; ++p)
        #pragma unroll
        for (int ct = 0; ct < 2; ++ct) {
            int cc = p * 128 + c0w + ct * 16 + l16;
            qsv[p][ct] = Qrow[cc];
            bmv[p][ct] = bem[cc] + 1.0f;
            bav[p][ct] = bea[cc];
        }
    #pragma unroll
    for (int ct = 0; ct < 2; ++ct) bo[ct] = beo[wave * 32 + ct * 16 + l16];

    // ---- prologue: prefetch tile 0 (e rows + K values) into registers
    float4 f[8];
    #pragma unroll
    for (int it = 0; it < 8; ++it)
        f[it] = ((const float4*)eBase)[tid + it * 256];
    short4 kpf[16];
    #pragma unroll
    for (int p = 0; p < 2; ++p)
        #pragma unroll
        for (int mc = 0; mc < 4; ++mc)
            #pragma unroll
            for (int ct = 0; ct < 2; ++ct) {
                int cc = p * 128 + c0w + ct * 16 + l16;
                kpf[p * 8 + mc * 2 + ct] =
                    *(const short4*)&kB[(size_t)cc * 256 + mc * 16 + q * 4];
            }

    for (int t = 0; t < 4; ++t) {
        const int j0  = t * 64;
        const int j0n = ((t + 1) & 3) * 64;   // next tile (wraps; redundant on t=3)

        // ---- write current e tile from prefetch regs to LDS
        #pragma unroll
        for (int it = 0; it < 8; ++it) {
            int idx4 = tid + it * 256;
            int elem = idx4 * 4, row = elem >> 7, col = elem & 127;
            short4 pk = make_short4((short)f2bf(f[it].x), (short)f2bf(f[it].y),
                                    (short)f2bf(f[it].z), (short)f2bf(f[it].w));
            *(short4*)&sE[row * 140 + col] = pk;
        }
        __syncthreads();   // barrier A: sE ready, sY(t-1) fully consumed

        // ---- issue e prefetch for next tile (lands during this tile's compute)
        {
            const float4* eN = (const float4*)(eBase + (size_t)j0n * ED);
            #pragma unroll
            for (int it = 0; it < 8; ++it)
                f[it] = eN[tid + it * 256];
        }

        // ---- GEMM1 + combine, 2 passes over column halves
        #pragma unroll
        for (int p = 0; p < 2; ++p) {
            const int c0 = p * 128 + c0w;
            short8 B1[4][2], B2[4][2];
            #pragma unroll
            for (int ks = 0; ks < 4; ++ks)
                #pragma unroll
                for (int ct = 0; ct < 2; ++ct) {
                    int n = c0 + ct * 16 + l16;
                    B1[ks][ct] = *(const short8*)&WemT[n * 128 + ks * 32 + q * 8];
                    B2[ks][ct] = *(const short8*)&WeaT[n * 128 + ks * 32 + q * 8];
                }
            #pragma unroll
            for (int mc = 0; mc < 4; ++mc) {
                const int m0 = mc * 16;
                f32x4 aE1[2] = {}, aE2[2] = {};
                #pragma unroll
                for (int ks = 0; ks < 4; ++ks) {
                    short8 a = *(const short8*)&sE[(m0 + l16) * 140 + ks * 32 + q * 8];
                    aE1[0] = MFMA16(a, B1[ks][0], aE1[0]);
                    aE1[1] = MFMA16(a, B1[ks][1], aE1[1]);
                    aE2[0] = MFMA16(a, B2[ks][0], aE2[0]);
                    aE2[1] = MFMA16(a, B2[ks][1], aE2[1]);
                }
                #pragma unroll
                for (int ct = 0; ct < 2; ++ct) {
                    short4 kv4 = kpf[p * 8 + mc * 2 + ct];
                    float kv[4] = { bf2f((unsigned short)kv4.x), bf2f((unsigned short)kv4.y),
                                    bf2f((unsigned short)kv4.z), bf2f((unsigned short)kv4.w) };
                    int cc = c0 + ct * 16 + l16;
                    #pragma unroll
                    for (int r = 0; r < 4; ++r) {
                        float y = qsv[p][ct] * kv[r] * (aE1[ct][r] + bmv[p][ct])
                                  + (aE2[ct][r] + bav[p][ct]);
                        sY[(m0 + q * 4 + r) * 264 + cc] = f2bf(y);
                    }
                }
            }
        }
        __syncthreads();   // barrier B: sY ready

        // ---- issue K prefetch for next tile (lands during GEMM2)
        #pragma unroll
        for (int p = 0; p < 2; ++p)
            #pragma unroll
            for (int mc = 0; mc < 4; ++mc)
                #pragma unroll
                for (int ct = 0; ct < 2; ++ct) {
                    int cc = p * 128 + c0w + ct * 16 + l16;
                    kpf[p * 8 + mc * 2 + ct] =
                        *(const short4*)&kB[(size_t)cc * 256 + j0n + mc * 16 + q * 4];
                }

        // ---- GEMM2: newE[64 x 128] = Y @ Weo ; wave owns 32-col n-slice
        short8 B3[8][2];
        #pragma unroll
        for (int ks = 0; ks < 8; ++ks)
            #pragma unroll
            for (int ct = 0; ct < 2; ++ct)
                B3[ks][ct] = *(const short8*)&WeoT[(wave * 32 + ct * 16 + l16) * 256 + ks * 32 + q * 8];
        f32x4 acc2[4][2] = {};
        #pragma unroll
        for (int ks = 0; ks < 8; ++ks) {
            #pragma unroll
            for (int mt = 0; mt < 4; ++mt) {
                short8 a = *(const short8*)&sY[(mt * 16 + l16) * 264 + ks * 32 + q * 8];
                acc2[mt][0] = MFMA16(a, B3[ks][0], acc2[mt][0]);
                acc2[mt][1] = MFMA16(a, B3[ks][1], acc2[mt][1]);
            }
        }
        float* outBase = outE + (size_t)((b * NN + i) * NN + j0) * ED;
        #pragma unroll
        for (int mt = 0; mt < 4; ++mt)
            #pragma unroll
            for (int ct = 0; ct < 2; ++ct) {
                int col = wave * 32 + ct * 16 + l16;
                #pragma unroll
                for (int r = 0; r < 4; ++r)
                    outBase[(size_t)(mt * 16 + q * 4 + r) * ED + col] = acc2[mt][ct][r] + bo[ct];
            }
        // no barrier needed here: barrier A of next tile orders sE/sY writes
    }
}

extern "C" void kernel_launch(void* const* d_in, const int* in_sizes, int n_in,
                              void* d_out, int out_size, void* d_ws, size_t ws_size,
                              hipStream_t stream)
{
    const float* x   = (const float*)d_in[0];
    const float* e   = (const float*)d_in[1];
    const float* Wq  = (const float*)d_in[2];
    const float* bq  = (const float*)d_in[3];
    const float* Wk  = (const float*)d_in[4];
    const float* bk  = (const float*)d_in[5];
    const float* Wv  = (const float*)d_in[6];
    const float* bv  = (const float*)d_in[7];
    const float* Wem = (const float*)d_in[8];
    const float* bem = (const float*)d_in[9];
    const float* Wea = (const float*)d_in[10];
    const float* bea = (const float*)d_in[11];
    const float* Wxo = (const float*)d_in[12];
    const float* bxo = (const float*)d_in[13];
    const float* Weo = (const float*)d_in[14];
    const float* beo = (const float*)d_in[15];

    float* outX = (float*)d_out;                 // newX: 262144 f32
    float* outE = (float*)d_out + 262144;        // newE: 33554432 f32

    float* Qs           = (float*)d_ws;          // [1024][256] f32 (scaled)
    unsigned short* Kbf = (unsigned short*)(Qs + 262144);  // [4][256 c][256 j] bf16
    short* WqT  = (short*)(Kbf + 262144);        // [256][256] bf16
    short* WkT  = WqT + 65536;
    short* WvT  = WkT + 65536;
    short* WxoT = WvT + 65536;
    short* WemT = WxoT + 65536;                  // [256][128] bf16
    short* WeaT = WemT + 32768;
    short* WeoT = WeaT + 32768;                  // [128][256] bf16

    hipLaunchKernelGGL(wprep_kernel, dim3(352), dim3(256), 0, stream,
                       Wq, Wk, Wv, Wxo, Wem, Wea, Weo,
                       WqT, WkT, WvT, WxoT, WemT, WeaT, WeoT);
    hipLaunchKernelGGL(proj_qk_kernel, dim3(32), dim3(512), 0, stream,
                       x, WqT, WkT, bq, bk, Qs, Kbf);
    hipLaunchKernelGGL(proj_vx_kernel, dim3(16), dim3(512), 0, stream,
                       x, WvT, bv, WxoT, bxo, outX);
    hipLaunchKernelGGL(fused_edge_kernel, dim3(1024), dim3(256), 0, stream,
                       e, Qs, Kbf, WemT, WeaT, WeoT, bem, bea, beo, outE);
}